// Round 1
// baseline (781.477 us; speedup 1.0000x reference)
//
#include <hip/hip_runtime.h>
#include <hip/hip_bf16.h>
#include <cstdint>

typedef float  f32x4 __attribute__((ext_vector_type(4)));
typedef float  f32x2 __attribute__((ext_vector_type(2)));
typedef short  s16x4 __attribute__((ext_vector_type(4)));
typedef short  s16x8 __attribute__((ext_vector_type(8)));
typedef __bf16 bf16x8 __attribute__((ext_vector_type(8)));

static __device__ __forceinline__ unsigned short f2bf(float f) {
  union { float f; unsigned u; } v; v.f = f;
  unsigned r = v.u + 0x7fffu + ((v.u >> 16) & 1u);   // RTNE
  return (unsigned short)(r >> 16);
}

static __device__ __forceinline__ f32x4 mfma16(bf16x8 a, bf16x8 b, f32x4 c) {
  return __builtin_amdgcn_mfma_f32_16x16x32_bf16(a, b, c, 0, 0, 0);
}

// C[128 x 128-slice] = X[128 x K] @ W[K x *] (column slice c*128), bf16 MFMA, fp32 acc.
// FUSE2:  h=relu(C+b1); P = h @ W2slice; atomicAdd(m1, P/64)   (per-ROI MLP branch)
// !FUSE2: out[m][c*128+n] = C + bias                            (final y2@Wo+bo)
template<bool FUSE2>
__global__ __launch_bounds__(256)
void gemm_kernel(const float* __restrict__ X, int ldx, long xrStride,
                 const float* __restrict__ W, int ldw, long wrStride,
                 const float* __restrict__ bias, int bStride,
                 const float* __restrict__ W2,
                 float* __restrict__ outBase,
                 int kSteps, int cBlocks)
{
  __shared__ short lds_a[128 * 40];    // [m][k] bf16, rows padded 32->40 elems
  __shared__ short lds_b[128 * 40];    // [n][k] bf16 (k-contiguous for B frags)
  __shared__ short lds_h[128 * 136];   // layer2 A: [m][kh] bf16
  __shared__ short lds_w2[32 * 136];   // layer2 B: [o][kh] bf16 (o>=20 zero)
  __shared__ float biasS[128];

  const int bid = blockIdx.x;
  const int r = bid / cBlocks;
  const int c = bid % cBlocks;

  const float* xr = X + (long)r * xrStride;
  const float* wr = W + (long)r * wrStride + c * 128;
  const float* bp = bias + (long)r * bStride + c * 128;

  const int t = threadIdx.x;
  const int lane = t & 63;
  const int w = t >> 6;                 // wave id 0..3

  if (t < 128) biasS[t] = bp[t];

  // staging maps
  const int amRow = t >> 3;             // 0..31 (+mi*32)
  const int akCol = (t & 7) * 4;        // k offset 0..28
  const int bn2   = (t & 63) * 2;       // 0..126 (pair of n)
  const int bkk   = w;                  // k-chunk 0..3 (8 k each)

  f32x4 aR[4];
  f32x2 bR[8];

  auto loadTile = [&](int ks) {
    const float* xp = xr + (long)amRow * ldx + ks * 32 + akCol;
    aR[0] = *(const f32x4*)xp;
    aR[1] = *(const f32x4*)(xp + (long)32 * ldx);
    aR[2] = *(const f32x4*)(xp + (long)64 * ldx);
    aR[3] = *(const f32x4*)(xp + (long)96 * ldx);
    const float* wp = wr + (long)(ks * 32 + bkk * 8) * ldw + bn2;
#pragma unroll
    for (int j = 0; j < 8; j++) bR[j] = *(const f32x2*)(wp + (long)j * ldw);
  };

  auto storeTile = [&]() {
#pragma unroll
    for (int mi = 0; mi < 4; mi++) {
      s16x4 v;
      v[0] = (short)f2bf(aR[mi][0]); v[1] = (short)f2bf(aR[mi][1]);
      v[2] = (short)f2bf(aR[mi][2]); v[3] = (short)f2bf(aR[mi][3]);
      *(s16x4*)&lds_a[(mi * 32 + amRow) * 40 + akCol] = v;
    }
    s16x8 v0, v1;
#pragma unroll
    for (int j = 0; j < 8; j++) {
      v0[j] = (short)f2bf(bR[j][0]);
      v1[j] = (short)f2bf(bR[j][1]);
    }
    *(s16x8*)&lds_b[bn2 * 40 + bkk * 8] = v0;
    *(s16x8*)&lds_b[(bn2 + 1) * 40 + bkk * 8] = v1;
  };

  // wave tiling: 2x2 waves, each 64x64 via 4x4 grid of 16x16x32 MFMA
  const int wm = w & 1, wn = w >> 1;
  const int mBase = wm * 64, nBase = wn * 64;
  const int lm = lane & 15, lg = lane >> 4;

  f32x4 acc[4][4];
#pragma unroll
  for (int i = 0; i < 4; i++)
#pragma unroll
    for (int j = 0; j < 4; j++) acc[i][j] = f32x4{0.f, 0.f, 0.f, 0.f};

  loadTile(0);
  for (int ks = 0; ks < kSteps; ks++) {
    __syncthreads();
    storeTile();
    __syncthreads();
    if (ks + 1 < kSteps) loadTile(ks + 1);
    bf16x8 af[4], bf[4];
#pragma unroll
    for (int i = 0; i < 4; i++) {
      af[i] = *(const bf16x8*)&lds_a[(mBase + i * 16 + lm) * 40 + lg * 8];
      bf[i] = *(const bf16x8*)&lds_b[(nBase + i * 16 + lm) * 40 + lg * 8];
    }
#pragma unroll
    for (int mi = 0; mi < 4; mi++)
#pragma unroll
      for (int ni = 0; ni < 4; ni++)
        acc[mi][ni] = mfma16(af[mi], bf[ni], acc[mi][ni]);
  }

  if constexpr (FUSE2) {
    // h = relu(acc + b1) -> lds_h (bf16, A-layout [m][kh=n])
#pragma unroll
    for (int mi = 0; mi < 4; mi++)
#pragma unroll
      for (int ni = 0; ni < 4; ni++) {
        const int col = nBase + ni * 16 + lm;
        const float bv = biasS[col];
#pragma unroll
        for (int i = 0; i < 4; i++) {
          const int row = mBase + mi * 16 + lg * 4 + i;
          float v = acc[mi][ni][i] + bv;
          v = v > 0.f ? v : 0.f;
          lds_h[row * 136 + col] = (short)f2bf(v);
        }
      }
    // stage W2 slice [kh 0..127][o 0..19] -> lds_w2[o][kh], zero-pad o>=20
    const float* w2r = W2 + (long)r * (512 * 20) + (long)c * 128 * 20;
#pragma unroll
    for (int i = 0; i < 16; i++) {
      const int idx = t * 16 + i;           // 0..4095
      const int o = idx >> 7, kh = idx & 127;
      const float v = (o < 20) ? w2r[(long)kh * 20 + o] : 0.f;
      lds_w2[o * 136 + kh] = (short)f2bf(v);
    }
    __syncthreads();
    // layer-2: wave w handles m in [w*32, w*32+32); n(=o) 0..31; K=128
    f32x4 acc2[2][2];
#pragma unroll
    for (int i = 0; i < 2; i++)
#pragma unroll
      for (int j = 0; j < 2; j++) acc2[i][j] = f32x4{0.f, 0.f, 0.f, 0.f};
#pragma unroll
    for (int ks2 = 0; ks2 < 4; ks2++) {
      bf16x8 a0 = *(const bf16x8*)&lds_h[(w * 32 + lm) * 136 + ks2 * 32 + lg * 8];
      bf16x8 a1 = *(const bf16x8*)&lds_h[(w * 32 + 16 + lm) * 136 + ks2 * 32 + lg * 8];
      bf16x8 b0 = *(const bf16x8*)&lds_w2[lm * 136 + ks2 * 32 + lg * 8];
      bf16x8 b1v = *(const bf16x8*)&lds_w2[(16 + lm) * 136 + ks2 * 32 + lg * 8];
      acc2[0][0] = mfma16(a0, b0, acc2[0][0]);
      acc2[0][1] = mfma16(a0, b1v, acc2[0][1]);
      acc2[1][0] = mfma16(a1, b0, acc2[1][0]);
      acc2[1][1] = mfma16(a1, b1v, acc2[1][1]);
    }
#pragma unroll
    for (int mi = 0; mi < 2; mi++)
#pragma unroll
      for (int ni = 0; ni < 2; ni++)
#pragma unroll
        for (int i = 0; i < 4; i++) {
          const int m = w * 32 + mi * 16 + lg * 4 + i;
          const int o = ni * 16 + lm;
          if (o < 20)
            atomicAdd(&outBase[m * 20 + o], acc2[mi][ni][i] * (1.f / 64.f));
        }
  } else {
    float* outp = outBase + c * 128;
#pragma unroll
    for (int mi = 0; mi < 4; mi++)
#pragma unroll
      for (int ni = 0; ni < 4; ni++) {
        const int col = nBase + ni * 16 + lm;
        const float bv = biasS[col];
#pragma unroll
        for (int i = 0; i < 4; i++) {
          const int row = mBase + mi * 16 + lg * 4 + i;
          outp[(long)row * 6400 + col] = acc[mi][ni][i] + bv;
        }
      }
  }
}

// m1 init: mean over r of b2 (the per-ROI bias of layer 2); K1 atomically adds the rest.
__global__ void k_init_m1(const float* __restrict__ b2, float* __restrict__ m1) {
  const int i = blockIdx.x * blockDim.x + threadIdx.x;
  if (i >= 128 * 20) return;
  const int o = i % 20;
  float s = 0.f;
  for (int r = 0; r < 64; r++) s += b2[r * 20 + o];
  m1[i] = s * (1.f / 64.f);
}

// generic small FC: out[b][j] = act(bias[j] + sum_k in[b][k] * W[k][j]), B=128 rows
__global__ void k_fc(const float* __restrict__ in, const float* __restrict__ Wt,
                     const float* __restrict__ bias, float* __restrict__ out,
                     int K, int N, int doRelu)
{
  const int i = blockIdx.x * blockDim.x + threadIdx.x;
  const int b = i / N;
  if (b >= 128) return;
  const int j = i - b * N;
  float s = bias[j];
  const float* ip = in + (long)b * K;
  for (int k = 0; k < K; k++) s += ip[k] * Wt[(long)k * N + j];
  out[i] = (doRelu && s < 0.f) ? 0.f : s;
}

extern "C" void kernel_launch(void* const* d_in, const int* in_sizes, int n_in,
                              void* d_out, int out_size, void* d_ws, size_t ws_size,
                              hipStream_t stream)
{
  const float* x   = (const float*)d_in[0];
  const float* W1  = (const float*)d_in[3];
  const float* b1  = (const float*)d_in[4];
  const float* W2  = (const float*)d_in[5];
  const float* b2  = (const float*)d_in[6];
  const float* Wg1 = (const float*)d_in[7];
  const float* bg1 = (const float*)d_in[8];
  const float* Wg2 = (const float*)d_in[9];
  const float* bg2 = (const float*)d_in[10];
  const float* Wf1 = (const float*)d_in[11];
  const float* bf1 = (const float*)d_in[12];
  const float* Wf2 = (const float*)d_in[13];
  const float* bf2 = (const float*)d_in[14];
  const float* Wo  = (const float*)d_in[15];
  const float* bo  = (const float*)d_in[16];
  float* out = (float*)d_out;

  float* ws = (float*)d_ws;
  float* m1 = ws;            // 2560 floats
  float* g1 = ws + 4096;     // 8192
  float* g2 = ws + 16384;    // 16384
  float* y1 = ws + 32768;    // 65536
  float* y2 = ws + 98304;    // 131072

  k_init_m1<<<10, 256, 0, stream>>>(b2, m1);
  // per-ROI MLP (dominant): 64 ROIs x 4 HID-slices
  gemm_kernel<true><<<256, 256, 0, stream>>>(x, 2048, (long)128 * 2048,
                                             W1, 512, (long)2048 * 512,
                                             b1, 512, W2, m1, 64, 4);
  // collapsed-GCN + FC chain
  k_fc<<<32, 256, 0, stream>>>(m1, Wg1, bg1, g1, 20, 64, 1);
  k_fc<<<64, 256, 0, stream>>>(g1, Wg2, bg2, g2, 64, 128, 1);
  k_fc<<<256, 256, 0, stream>>>(g2, Wf1, bf1, y1, 128, 512, 1);
  k_fc<<<512, 256, 0, stream>>>(y1, Wf2, bf2, y2, 512, 1024, 1);
  // out = y2 @ Wo + bo : 50 column blocks of 128
  gemm_kernel<false><<<50, 256, 0, stream>>>(y2, 1024, 0,
                                             Wo, 6400, 0,
                                             bo, 0, nullptr, out, 32, 50);
}

// Round 2
// 547.957 us; speedup vs baseline: 1.4262x; 1.4262x over previous
//
#include <hip/hip_runtime.h>
#include <hip/hip_bf16.h>
#include <cstdint>

typedef float  f32x4 __attribute__((ext_vector_type(4)));
typedef float  f32x2 __attribute__((ext_vector_type(2)));
typedef short  s16x4 __attribute__((ext_vector_type(4)));
typedef short  s16x8 __attribute__((ext_vector_type(8)));
typedef __bf16 bf16x8 __attribute__((ext_vector_type(8)));

static __device__ __forceinline__ unsigned short f2bf(float f) {
  union { float f; unsigned u; } v; v.f = f;
  unsigned r = v.u + 0x7fffu + ((v.u >> 16) & 1u);   // RTNE
  return (unsigned short)(r >> 16);
}

static __device__ __forceinline__ f32x4 mfma16(bf16x8 a, bf16x8 b, f32x4 c) {
  return __builtin_amdgcn_mfma_f32_16x16x32_bf16(a, b, c, 0, 0, 0);
}

// ---------------------------------------------------------------------------
// k_mlp: fused per-ROI 2-layer MLP. Grid 512 = 64 ROIs x 8 HID-slices of 64.
// Tile: M=128 (batch) x N=64 (HID slice), K=2048 in 64 steps of 32.
// Epilogue: h = relu(C + b1slice) [128x64] -> P = h @ W2slice [64x20]
//           atomicAdd(m1, P/64)  (K-partial over HID slices + ROI mean)
// 2 blocks/CU (38.7 KB LDS) -> 2 waves/SIMD for barrier-drain overlap.
// ---------------------------------------------------------------------------
__global__ __launch_bounds__(256)
void k_mlp(const float* __restrict__ X, const float* __restrict__ W1,
           const float* __restrict__ b1, const float* __restrict__ W2,
           float* __restrict__ m1)
{
  __shared__ short lds_a[128 * 40];   // [m][k] bf16, k padded 32->40
  __shared__ short lds_b[64 * 40];    // [n][k] bf16
  __shared__ short lds_h[128 * 72];   // layer2 A: [m][kh] bf16, kh padded 64->72
  __shared__ short lds_w2[32 * 72];   // layer2 B: [o][kh] bf16 (o>=20 zero)
  __shared__ float biasS[64];

  const int bid = blockIdx.x;
  // XCD swizzle: the 8 c-slices of one r land on the same XCD (bid % 8 const)
  const int r = (bid & 7) + ((bid >> 6) << 3);
  const int c = (bid >> 3) & 7;

  const float* xr = X + (long)r * (128 * 2048);
  const float* wr = W1 + (long)r * (2048 * 512) + c * 64;
  const float* bp = b1 + (long)r * 512 + c * 64;

  const int t = threadIdx.x;
  const int lane = t & 63;
  const int w = t >> 6;

  if (t < 64) biasS[t] = bp[t];

  const int amRow = t >> 3;            // 0..31 (+mi*32)
  const int akCol = (t & 7) * 4;
  const int bn = t & 63;               // n column
  const int bkk = w;                   // k-chunk 0..3, 8 k each

  f32x4 aR[4];
  float bR[8];

  auto loadTile = [&](int ks) {
    const float* xp = xr + (long)amRow * 2048 + ks * 32 + akCol;
    aR[0] = *(const f32x4*)xp;
    aR[1] = *(const f32x4*)(xp + 32 * 2048);
    aR[2] = *(const f32x4*)(xp + 64 * 2048);
    aR[3] = *(const f32x4*)(xp + 96 * 2048);
    const float* wp = wr + (long)(ks * 32 + bkk * 8) * 512 + bn;
#pragma unroll
    for (int j = 0; j < 8; j++) bR[j] = wp[(long)j * 512];
  };

  auto storeTile = [&]() {
#pragma unroll
    for (int mi = 0; mi < 4; mi++) {
      s16x4 v;
      v[0] = (short)f2bf(aR[mi][0]); v[1] = (short)f2bf(aR[mi][1]);
      v[2] = (short)f2bf(aR[mi][2]); v[3] = (short)f2bf(aR[mi][3]);
      *(s16x4*)&lds_a[(mi * 32 + amRow) * 40 + akCol] = v;
    }
    s16x8 v;
#pragma unroll
    for (int j = 0; j < 8; j++) v[j] = (short)f2bf(bR[j]);
    *(s16x8*)&lds_b[bn * 40 + bkk * 8] = v;
  };

  // 4 waves as 2(m) x 2(n): each wave 64m x 32n = 4x2 MFMAs of 16x16x32
  const int wm = w & 1, wn = w >> 1;
  const int mBase = wm * 64, nBase = wn * 32;
  const int lm = lane & 15, lg = lane >> 4;

  f32x4 acc[4][2];
#pragma unroll
  for (int i = 0; i < 4; i++)
#pragma unroll
    for (int j = 0; j < 2; j++) acc[i][j] = f32x4{0.f, 0.f, 0.f, 0.f};

  loadTile(0);
  for (int ks = 0; ks < 64; ks++) {
    __syncthreads();
    storeTile();
    __syncthreads();
    if (ks + 1 < 64) loadTile(ks + 1);
    bf16x8 af[4], bfr[2];
#pragma unroll
    for (int i = 0; i < 4; i++)
      af[i] = *(const bf16x8*)&lds_a[(mBase + i * 16 + lm) * 40 + lg * 8];
#pragma unroll
    for (int j = 0; j < 2; j++)
      bfr[j] = *(const bf16x8*)&lds_b[(nBase + j * 16 + lm) * 40 + lg * 8];
#pragma unroll
    for (int mi = 0; mi < 4; mi++)
#pragma unroll
      for (int ni = 0; ni < 2; ni++)
        acc[mi][ni] = mfma16(af[mi], bfr[ni], acc[mi][ni]);
  }

  // h = relu(acc + b1) -> lds_h (bf16, A-layout [m][kh])
#pragma unroll
  for (int mi = 0; mi < 4; mi++)
#pragma unroll
    for (int ni = 0; ni < 2; ni++) {
      const int col = nBase + ni * 16 + lm;
      const float bv = biasS[col];
#pragma unroll
      for (int i = 0; i < 4; i++) {
        const int row = mBase + mi * 16 + lg * 4 + i;
        float v = acc[mi][ni][i] + bv;
        v = v > 0.f ? v : 0.f;
        lds_h[row * 72 + col] = (short)f2bf(v);
      }
    }
  // stage W2 slice [kh 0..63][o 0..19] -> lds_w2[o][kh], zero-pad o>=20
  {
    const float* w2r = W2 + (long)r * (512 * 20) + (long)c * 64 * 20;
#pragma unroll
    for (int i = 0; i < 8; i++) {
      const int idx = t * 8 + i;            // 0..2047
      const int o = idx >> 6, kh = idx & 63;
      const float v = (o < 20) ? w2r[(long)kh * 20 + o] : 0.f;
      lds_w2[o * 72 + kh] = (short)f2bf(v);
    }
  }
  __syncthreads();
  // layer-2: wave w -> m rows [w*32, w*32+32), o 0..31, K=64 (2 steps)
  f32x4 acc2[2][2];
#pragma unroll
  for (int i = 0; i < 2; i++)
#pragma unroll
    for (int j = 0; j < 2; j++) acc2[i][j] = f32x4{0.f, 0.f, 0.f, 0.f};
#pragma unroll
  for (int ks2 = 0; ks2 < 2; ks2++) {
    bf16x8 a0 = *(const bf16x8*)&lds_h[(w * 32 + lm) * 72 + ks2 * 32 + lg * 8];
    bf16x8 a1 = *(const bf16x8*)&lds_h[(w * 32 + 16 + lm) * 72 + ks2 * 32 + lg * 8];
    bf16x8 b0 = *(const bf16x8*)&lds_w2[lm * 72 + ks2 * 32 + lg * 8];
    bf16x8 b1v = *(const bf16x8*)&lds_w2[(16 + lm) * 72 + ks2 * 32 + lg * 8];
    acc2[0][0] = mfma16(a0, b0, acc2[0][0]);
    acc2[0][1] = mfma16(a0, b1v, acc2[0][1]);
    acc2[1][0] = mfma16(a1, b0, acc2[1][0]);
    acc2[1][1] = mfma16(a1, b1v, acc2[1][1]);
  }
#pragma unroll
  for (int mi = 0; mi < 2; mi++)
#pragma unroll
    for (int ni = 0; ni < 2; ni++)
#pragma unroll
      for (int i = 0; i < 4; i++) {
        const int m = w * 32 + mi * 16 + lg * 4 + i;
        const int o = ni * 16 + lm;
        if (o < 20)
          atomicAdd(&m1[m * 20 + o], acc2[mi][ni][i] * (1.f / 64.f));
      }
}

// ---------------------------------------------------------------------------
// gemm_plain: out[128 x 128-slice] = act(X[128,K] @ W[K,N] + bias), grid=N/128
// ---------------------------------------------------------------------------
template<int RELU>
__global__ __launch_bounds__(256)
void gemm_plain(const float* __restrict__ X, int ldx,
                const float* __restrict__ W, int ldw,
                const float* __restrict__ bias,
                float* __restrict__ out, int ldo, int kSteps)
{
  __shared__ short lds_a[128 * 40];
  __shared__ short lds_b[128 * 40];
  __shared__ float biasS[128];

  const int c = blockIdx.x;
  const int t = threadIdx.x;
  const int lane = t & 63;
  const int w = t >> 6;

  if (t < 128) biasS[t] = bias[c * 128 + t];

  const int amRow = t >> 3;
  const int akCol = (t & 7) * 4;
  const int bn2   = (t & 63) * 2;
  const int bkk   = w;

  f32x4 aR[4];
  f32x2 bR[8];

  auto loadTile = [&](int ks) {
    const float* xp = X + (long)amRow * ldx + ks * 32 + akCol;
    aR[0] = *(const f32x4*)xp;
    aR[1] = *(const f32x4*)(xp + (long)32 * ldx);
    aR[2] = *(const f32x4*)(xp + (long)64 * ldx);
    aR[3] = *(const f32x4*)(xp + (long)96 * ldx);
    const float* wp = W + (long)(ks * 32 + bkk * 8) * ldw + c * 128 + bn2;
#pragma unroll
    for (int j = 0; j < 8; j++) bR[j] = *(const f32x2*)(wp + (long)j * ldw);
  };

  auto storeTile = [&]() {
#pragma unroll
    for (int mi = 0; mi < 4; mi++) {
      s16x4 v;
      v[0] = (short)f2bf(aR[mi][0]); v[1] = (short)f2bf(aR[mi][1]);
      v[2] = (short)f2bf(aR[mi][2]); v[3] = (short)f2bf(aR[mi][3]);
      *(s16x4*)&lds_a[(mi * 32 + amRow) * 40 + akCol] = v;
    }
    s16x8 v0, v1;
#pragma unroll
    for (int j = 0; j < 8; j++) {
      v0[j] = (short)f2bf(bR[j][0]);
      v1[j] = (short)f2bf(bR[j][1]);
    }
    *(s16x8*)&lds_b[bn2 * 40 + bkk * 8] = v0;
    *(s16x8*)&lds_b[(bn2 + 1) * 40 + bkk * 8] = v1;
  };

  const int wm = w & 1, wn = w >> 1;
  const int mBase = wm * 64, nBase = wn * 64;
  const int lm = lane & 15, lg = lane >> 4;

  f32x4 acc[4][4];
#pragma unroll
  for (int i = 0; i < 4; i++)
#pragma unroll
    for (int j = 0; j < 4; j++) acc[i][j] = f32x4{0.f, 0.f, 0.f, 0.f};

  loadTile(0);
  for (int ks = 0; ks < kSteps; ks++) {
    __syncthreads();
    storeTile();
    __syncthreads();
    if (ks + 1 < kSteps) loadTile(ks + 1);
    bf16x8 af[4], bfr[4];
#pragma unroll
    for (int i = 0; i < 4; i++) {
      af[i]  = *(const bf16x8*)&lds_a[(mBase + i * 16 + lm) * 40 + lg * 8];
      bfr[i] = *(const bf16x8*)&lds_b[(nBase + i * 16 + lm) * 40 + lg * 8];
    }
#pragma unroll
    for (int mi = 0; mi < 4; mi++)
#pragma unroll
      for (int ni = 0; ni < 4; ni++)
        acc[mi][ni] = mfma16(af[mi], bfr[ni], acc[mi][ni]);
  }

  float* outp = out + c * 128;
#pragma unroll
  for (int mi = 0; mi < 4; mi++)
#pragma unroll
    for (int ni = 0; ni < 4; ni++) {
      const int col = nBase + ni * 16 + lm;
      const float bv = biasS[col];
#pragma unroll
      for (int i = 0; i < 4; i++) {
        const int row = mBase + mi * 16 + lg * 4 + i;
        float v = acc[mi][ni][i] + bv;
        if (RELU) v = v > 0.f ? v : 0.f;
        outp[(long)row * ldo + col] = v;
      }
    }
}

// m1 init: mean over r of b2; k_mlp atomically adds the rest.
__global__ void k_init_m1(const float* __restrict__ b2, float* __restrict__ m1) {
  const int i = blockIdx.x * blockDim.x + threadIdx.x;
  if (i >= 128 * 20) return;
  const int o = i % 20;
  float s = 0.f;
  for (int r = 0; r < 64; r++) s += b2[r * 20 + o];
  m1[i] = s * (1.f / 64.f);
}

// small FC, K fully unrolled (all W loads in flight) for latency
template<int K, int RELU>
__global__ void k_fc_small(const float* __restrict__ in, const float* __restrict__ Wt,
                           const float* __restrict__ bias, float* __restrict__ out,
                           int N)
{
  const int i = blockIdx.x * blockDim.x + threadIdx.x;
  const int b = i / N;
  if (b >= 128) return;
  const int j = i - b * N;
  float s = bias[j];
  const float* ip = in + (long)b * K;
#pragma unroll
  for (int k = 0; k < K; k++) s += ip[k] * Wt[k * N + j];
  out[i] = (RELU && s < 0.f) ? 0.f : s;
}

extern "C" void kernel_launch(void* const* d_in, const int* in_sizes, int n_in,
                              void* d_out, int out_size, void* d_ws, size_t ws_size,
                              hipStream_t stream)
{
  const float* x   = (const float*)d_in[0];
  const float* W1  = (const float*)d_in[3];
  const float* b1  = (const float*)d_in[4];
  const float* W2  = (const float*)d_in[5];
  const float* b2  = (const float*)d_in[6];
  const float* Wg1 = (const float*)d_in[7];
  const float* bg1 = (const float*)d_in[8];
  const float* Wg2 = (const float*)d_in[9];
  const float* bg2 = (const float*)d_in[10];
  const float* Wf1 = (const float*)d_in[11];
  const float* bf1 = (const float*)d_in[12];
  const float* Wf2 = (const float*)d_in[13];
  const float* bf2 = (const float*)d_in[14];
  const float* Wo  = (const float*)d_in[15];
  const float* bo  = (const float*)d_in[16];
  float* out = (float*)d_out;

  float* ws = (float*)d_ws;
  float* m1 = ws;            // 2560 floats
  float* g1 = ws + 4096;     // 8192
  float* g2 = ws + 16384;    // 16384
  float* y1 = ws + 32768;    // 65536
  float* y2 = ws + 98304;    // 131072

  k_init_m1<<<10, 256, 0, stream>>>(b2, m1);
  // dominant: per-ROI 2-layer MLP, 64 ROIs x 8 HID-slices
  k_mlp<<<512, 256, 0, stream>>>(x, W1, b1, W2, m1);
  // collapsed-GCN + FC chain
  k_fc_small<20, 1><<<32, 256, 0, stream>>>(m1, Wg1, bg1, g1, 64);
  k_fc_small<64, 1><<<64, 256, 0, stream>>>(g1, Wg2, bg2, g2, 128);
  gemm_plain<1><<<4,  256, 0, stream>>>(g2, 128,  Wf1, 512,  bf1, y1, 512, 4);
  gemm_plain<1><<<8,  256, 0, stream>>>(y1, 512,  Wf2, 1024, bf2, y2, 1024, 16);
  gemm_plain<0><<<50, 256, 0, stream>>>(y2, 1024, Wo,  6400, bo,  out, 6400, 32);
}

// Round 3
// 509.915 us; speedup vs baseline: 1.5326x; 1.0746x over previous
//
#include <hip/hip_runtime.h>
#include <hip/hip_bf16.h>
#include <cstdint>

typedef float  f32x4 __attribute__((ext_vector_type(4)));
typedef short  s16x4 __attribute__((ext_vector_type(4)));
typedef short  s16x8 __attribute__((ext_vector_type(8)));
typedef __bf16 bf16x8 __attribute__((ext_vector_type(8)));

static __device__ __forceinline__ unsigned short f2bf(float f) {
  union { float f; unsigned u; } v; v.f = f;
  unsigned r = v.u + 0x7fffu + ((v.u >> 16) & 1u);   // RTNE
  return (unsigned short)(r >> 16);
}

static __device__ __forceinline__ f32x4 mfma16(bf16x8 a, bf16x8 b, f32x4 c) {
  return __builtin_amdgcn_mfma_f32_16x16x32_bf16(a, b, c, 0, 0, 0);
}

// ---------------------------------------------------------------------------
// k_mlp: fused per-ROI 2-layer MLP. Grid 512 = 64 ROIs x 8 HID-slices of 64.
// Tile: M=128 (batch) x N=64 (HID slice), K=2048 in 32 steps of BK=64.
// Epilogue: h = relu(C + b1slice) -> P = h @ W2slice -> atomicAdd(m1, P/64).
// ~51 KB LDS -> 2 blocks/CU for barrier-drain overlap.
// ---------------------------------------------------------------------------
__global__ __launch_bounds__(256)
void k_mlp(const float* __restrict__ X, const float* __restrict__ W1,
           const float* __restrict__ b1, const float* __restrict__ W2,
           float* __restrict__ m1)
{
  __shared__ short lds_a[128 * 72];   // [m][k] bf16, k padded 64->72
  __shared__ short lds_b[64 * 72];    // [n][k] bf16
  __shared__ short lds_h[128 * 72];   // layer2 A: [m][kh] bf16
  __shared__ short lds_w2[32 * 72];   // layer2 B: [o][kh] bf16 (o>=20 zero)
  __shared__ float biasS[64];

  const int bid = blockIdx.x;
  // XCD swizzle: the 8 c-slices of one r land on the same XCD
  const int r = (bid & 7) + ((bid >> 6) << 3);
  const int c = (bid >> 3) & 7;

  const float* xr = X + (long)r * (128 * 2048);
  const float* wr = W1 + (long)r * (2048 * 512) + c * 64;
  const float* bp = b1 + (long)r * 512 + c * 64;

  const int t = threadIdx.x;
  const int lane = t & 63;
  const int w = t >> 6;

  if (t < 64) biasS[t] = bp[t];

  // staging maps (BK=64)
  const int aRow = t >> 2;             // 0..63 (+64 for second group)
  const int aCol = (t & 3) * 4;        // within-row float offset, +16j
  const int bn   = t & 63;
  const int bk0  = w * 8;              // k-chunk base: 0,8,16,24 (+32 for g=1)

  f32x4 aR[2][4];
  float bR[2][8];

  auto loadTile = [&](int ks) {
    const float* xp = xr + (long)aRow * 2048 + ks * 64 + aCol;
#pragma unroll
    for (int j = 0; j < 4; j++) {
      aR[0][j] = *(const f32x4*)(xp + 16 * j);
      aR[1][j] = *(const f32x4*)(xp + 64 * 2048 + 16 * j);
    }
    const float* wp = wr + (long)(ks * 64 + bk0) * 512 + bn;
#pragma unroll
    for (int g = 0; g < 2; g++)
#pragma unroll
      for (int j = 0; j < 8; j++)
        bR[g][j] = wp[(long)(g * 32 + j) * 512];
  };

  auto storeTile = [&]() {
#pragma unroll
    for (int g = 0; g < 2; g++)
#pragma unroll
      for (int j = 0; j < 4; j++) {
        s16x4 v;
        v[0] = (short)f2bf(aR[g][j][0]); v[1] = (short)f2bf(aR[g][j][1]);
        v[2] = (short)f2bf(aR[g][j][2]); v[3] = (short)f2bf(aR[g][j][3]);
        *(s16x4*)&lds_a[(aRow + 64 * g) * 72 + aCol + 16 * j] = v;
      }
#pragma unroll
    for (int g = 0; g < 2; g++) {
      s16x8 v;
#pragma unroll
      for (int j = 0; j < 8; j++) v[j] = (short)f2bf(bR[g][j]);
      *(s16x8*)&lds_b[bn * 72 + bk0 + g * 32] = v;
    }
  };

  // 4 waves as 2(m) x 2(n): each wave 64m x 32n; per step 4x2x2 MFMAs
  const int wm = w & 1, wn = w >> 1;
  const int mBase = wm * 64, nBase = wn * 32;
  const int lm = lane & 15, lg = lane >> 4;

  f32x4 acc[4][2];
#pragma unroll
  for (int i = 0; i < 4; i++)
#pragma unroll
    for (int j = 0; j < 2; j++) acc[i][j] = f32x4{0.f, 0.f, 0.f, 0.f};

  loadTile(0);
  for (int ks = 0; ks < 32; ks++) {
    __syncthreads();
    storeTile();
    __syncthreads();
    if (ks + 1 < 32) loadTile(ks + 1);
    bf16x8 af[2][4], bfr[2][2];
#pragma unroll
    for (int g = 0; g < 2; g++) {
#pragma unroll
      for (int i = 0; i < 4; i++)
        af[g][i] = *(const bf16x8*)&lds_a[(mBase + i * 16 + lm) * 72 + g * 32 + lg * 8];
#pragma unroll
      for (int j = 0; j < 2; j++)
        bfr[g][j] = *(const bf16x8*)&lds_b[(nBase + j * 16 + lm) * 72 + g * 32 + lg * 8];
    }
#pragma unroll
    for (int mi = 0; mi < 4; mi++)
#pragma unroll
      for (int ni = 0; ni < 2; ni++) {
        acc[mi][ni] = mfma16(af[0][mi], bfr[0][ni], acc[mi][ni]);
        acc[mi][ni] = mfma16(af[1][mi], bfr[1][ni], acc[mi][ni]);
      }
  }

  // h = relu(acc + b1) -> lds_h (bf16, A-layout [m][kh])
#pragma unroll
  for (int mi = 0; mi < 4; mi++)
#pragma unroll
    for (int ni = 0; ni < 2; ni++) {
      const int col = nBase + ni * 16 + lm;
      const float bv = biasS[col];
#pragma unroll
      for (int i = 0; i < 4; i++) {
        const int row = mBase + mi * 16 + lg * 4 + i;
        float v = acc[mi][ni][i] + bv;
        v = v > 0.f ? v : 0.f;
        lds_h[row * 72 + col] = (short)f2bf(v);
      }
    }
  // stage W2 slice [kh 0..63][o 0..19] -> lds_w2[o][kh], zero-pad o>=20
  {
    const float* w2r = W2 + (long)r * (512 * 20) + (long)c * 64 * 20;
#pragma unroll
    for (int i = 0; i < 8; i++) {
      const int idx = t * 8 + i;            // 0..2047
      const int o = idx >> 6, kh = idx & 63;
      const float v = (o < 20) ? w2r[(long)kh * 20 + o] : 0.f;
      lds_w2[o * 72 + kh] = (short)f2bf(v);
    }
  }
  __syncthreads();
  // layer-2: wave w -> m rows [w*32, w*32+32), o 0..31, K=64 (2 steps)
  f32x4 acc2[2][2];
#pragma unroll
  for (int i = 0; i < 2; i++)
#pragma unroll
    for (int j = 0; j < 2; j++) acc2[i][j] = f32x4{0.f, 0.f, 0.f, 0.f};
#pragma unroll
  for (int ks2 = 0; ks2 < 2; ks2++) {
    bf16x8 a0 = *(const bf16x8*)&lds_h[(w * 32 + lm) * 72 + ks2 * 32 + lg * 8];
    bf16x8 a1 = *(const bf16x8*)&lds_h[(w * 32 + 16 + lm) * 72 + ks2 * 32 + lg * 8];
    bf16x8 b0 = *(const bf16x8*)&lds_w2[lm * 72 + ks2 * 32 + lg * 8];
    bf16x8 b1v = *(const bf16x8*)&lds_w2[(16 + lm) * 72 + ks2 * 32 + lg * 8];
    acc2[0][0] = mfma16(a0, b0, acc2[0][0]);
    acc2[0][1] = mfma16(a0, b1v, acc2[0][1]);
    acc2[1][0] = mfma16(a1, b0, acc2[1][0]);
    acc2[1][1] = mfma16(a1, b1v, acc2[1][1]);
  }
#pragma unroll
  for (int mi = 0; mi < 2; mi++)
#pragma unroll
    for (int ni = 0; ni < 2; ni++)
#pragma unroll
      for (int i = 0; i < 4; i++) {
        const int m = w * 32 + mi * 16 + lg * 4 + i;
        const int o = ni * 16 + lm;
        if (o < 20)
          atomicAdd(&m1[m * 20 + o], acc2[mi][ni][i] * (1.f / 64.f));
      }
}

// ---------------------------------------------------------------------------
// gemm_n64: out[:, c*64 : c*64+64] = act(X[128,K] @ W[K,N] + bias)
// M=128 x N=64 tiles, BK=64, grid = N/64. Same wave layout as k_mlp.
// ---------------------------------------------------------------------------
template<int RELU>
__global__ __launch_bounds__(256)
void gemm_n64(const float* __restrict__ X, int ldx,
              const float* __restrict__ W, int ldw,
              const float* __restrict__ bias,
              float* __restrict__ out, int ldo, int kSteps)
{
  __shared__ short lds_a[128 * 72];
  __shared__ short lds_b[64 * 72];
  __shared__ float biasS[64];

  const int c = blockIdx.x;
  const int t = threadIdx.x;
  const int lane = t & 63;
  const int w = t >> 6;

  if (t < 64) biasS[t] = bias[c * 64 + t];

  const int aRow = t >> 2;
  const int aCol = (t & 3) * 4;
  const int bn   = t & 63;
  const int bk0  = w * 8;

  f32x4 aR[2][4];
  float bR[2][8];

  auto loadTile = [&](int ks) {
    const float* xp = X + (long)aRow * ldx + ks * 64 + aCol;
#pragma unroll
    for (int j = 0; j < 4; j++) {
      aR[0][j] = *(const f32x4*)(xp + 16 * j);
      aR[1][j] = *(const f32x4*)(xp + (long)64 * ldx + 16 * j);
    }
    const float* wp = W + (long)(ks * 64 + bk0) * ldw + c * 64 + bn;
#pragma unroll
    for (int g = 0; g < 2; g++)
#pragma unroll
      for (int j = 0; j < 8; j++)
        bR[g][j] = wp[(long)(g * 32 + j) * ldw];
  };

  auto storeTile = [&]() {
#pragma unroll
    for (int g = 0; g < 2; g++)
#pragma unroll
      for (int j = 0; j < 4; j++) {
        s16x4 v;
        v[0] = (short)f2bf(aR[g][j][0]); v[1] = (short)f2bf(aR[g][j][1]);
        v[2] = (short)f2bf(aR[g][j][2]); v[3] = (short)f2bf(aR[g][j][3]);
        *(s16x4*)&lds_a[(aRow + 64 * g) * 72 + aCol + 16 * j] = v;
      }
#pragma unroll
    for (int g = 0; g < 2; g++) {
      s16x8 v;
#pragma unroll
      for (int j = 0; j < 8; j++) v[j] = (short)f2bf(bR[g][j]);
      *(s16x8*)&lds_b[bn * 72 + bk0 + g * 32] = v;
    }
  };

  const int wm = w & 1, wn = w >> 1;
  const int mBase = wm * 64, nBase = wn * 32;
  const int lm = lane & 15, lg = lane >> 4;

  f32x4 acc[4][2];
#pragma unroll
  for (int i = 0; i < 4; i++)
#pragma unroll
    for (int j = 0; j < 2; j++) acc[i][j] = f32x4{0.f, 0.f, 0.f, 0.f};

  loadTile(0);
  for (int ks = 0; ks < kSteps; ks++) {
    __syncthreads();
    storeTile();
    __syncthreads();
    if (ks + 1 < kSteps) loadTile(ks + 1);
    bf16x8 af[2][4], bfr[2][2];
#pragma unroll
    for (int g = 0; g < 2; g++) {
#pragma unroll
      for (int i = 0; i < 4; i++)
        af[g][i] = *(const bf16x8*)&lds_a[(mBase + i * 16 + lm) * 72 + g * 32 + lg * 8];
#pragma unroll
      for (int j = 0; j < 2; j++)
        bfr[g][j] = *(const bf16x8*)&lds_b[(nBase + j * 16 + lm) * 72 + g * 32 + lg * 8];
    }
#pragma unroll
    for (int mi = 0; mi < 4; mi++)
#pragma unroll
      for (int ni = 0; ni < 2; ni++) {
        acc[mi][ni] = mfma16(af[0][mi], bfr[0][ni], acc[mi][ni]);
        acc[mi][ni] = mfma16(af[1][mi], bfr[1][ni], acc[mi][ni]);
      }
  }

  float* outp = out + c * 64;
#pragma unroll
  for (int mi = 0; mi < 4; mi++)
#pragma unroll
    for (int ni = 0; ni < 2; ni++) {
      const int col = nBase + ni * 16 + lm;
      const float bv = biasS[col];
#pragma unroll
      for (int i = 0; i < 4; i++) {
        const int row = mBase + mi * 16 + lg * 4 + i;
        float v = acc[mi][ni][i] + bv;
        if (RELU) v = v > 0.f ? v : 0.f;
        outp[(long)row * ldo + col] = v;
      }
    }
}

// m1 init: mean over r of b2; k_mlp atomically adds the rest.
__global__ void k_init_m1(const float* __restrict__ b2, float* __restrict__ m1) {
  const int i = blockIdx.x * blockDim.x + threadIdx.x;
  if (i >= 128 * 20) return;
  const int o = i % 20;
  float s = 0.f;
  for (int r = 0; r < 64; r++) s += b2[r * 20 + o];
  m1[i] = s * (1.f / 64.f);
}

// small FC, K fully unrolled (all W loads in flight) for latency
template<int K, int RELU>
__global__ void k_fc_small(const float* __restrict__ in, const float* __restrict__ Wt,
                           const float* __restrict__ bias, float* __restrict__ out,
                           int N)
{
  const int i = blockIdx.x * blockDim.x + threadIdx.x;
  const int b = i / N;
  if (b >= 128) return;
  const int j = i - b * N;
  float s = bias[j];
  const float* ip = in + (long)b * K;
#pragma unroll
  for (int k = 0; k < K; k++) s += ip[k] * Wt[k * N + j];
  out[i] = (RELU && s < 0.f) ? 0.f : s;
}

extern "C" void kernel_launch(void* const* d_in, const int* in_sizes, int n_in,
                              void* d_out, int out_size, void* d_ws, size_t ws_size,
                              hipStream_t stream)
{
  const float* x   = (const float*)d_in[0];
  const float* W1  = (const float*)d_in[3];
  const float* b1  = (const float*)d_in[4];
  const float* W2  = (const float*)d_in[5];
  const float* b2  = (const float*)d_in[6];
  const float* Wg1 = (const float*)d_in[7];
  const float* bg1 = (const float*)d_in[8];
  const float* Wg2 = (const float*)d_in[9];
  const float* bg2 = (const float*)d_in[10];
  const float* Wf1 = (const float*)d_in[11];
  const float* bf1 = (const float*)d_in[12];
  const float* Wf2 = (const float*)d_in[13];
  const float* bf2 = (const float*)d_in[14];
  const float* Wo  = (const float*)d_in[15];
  const float* bo  = (const float*)d_in[16];
  float* out = (float*)d_out;

  float* ws = (float*)d_ws;
  float* m1 = ws;            // 2560 floats
  float* g1 = ws + 4096;     // 8192
  float* g2 = ws + 16384;    // 16384
  float* y1 = ws + 32768;    // 65536
  float* y2 = ws + 98304;    // 131072

  k_init_m1<<<10, 256, 0, stream>>>(b2, m1);
  // dominant: per-ROI 2-layer MLP, 64 ROIs x 8 HID-slices
  k_mlp<<<512, 256, 0, stream>>>(x, W1, b1, W2, m1);
  // collapsed-GCN + FC chain
  k_fc_small<20, 1><<<32, 256, 0, stream>>>(m1, Wg1, bg1, g1, 64);
  k_fc_small<64, 1><<<64, 256, 0, stream>>>(g1, Wg2, bg2, g2, 128);
  gemm_n64<1><<<8,   256, 0, stream>>>(g2, 128,  Wf1, 512,  bf1, y1, 512, 2);
  gemm_n64<1><<<16,  256, 0, stream>>>(y1, 512,  Wf2, 1024, bf2, y2, 1024, 8);
  gemm_n64<0><<<100, 256, 0, stream>>>(y2, 1024, Wo,  6400, bo,  out, 6400, 16);
}